// Round 6
// baseline (963.257 us; speedup 1.0000x reference)
//
#include <hip/hip_runtime.h>
#include <hip/hip_bf16.h>

// Shapes: B=32 S=1024 D=256 V=50257 C=1000   (float tensors fp32; x int32; out fp32)
// conv1: groups=256, Cin/g=1, Cout/g=6, K=7, pad=6 -> L1=1030; fold -> 768 ch
// kmax k1=515 -> tanh -> conv2: groups=128, Cin/g=6, Cout/g=14, K=5, pad=4 -> L2=519
// fold -> 896 ch -> kmax 4 -> tanh -> (32,3584) @ wf^T(1000,3584) + bf
//
// R6: fp32 everywhere upstream of the kmax(515) (R5's bf16 emb caused rank flips ->
// position shifts -> 0.109 absmax). Coalesced gather -> E2[b][r4][l][4] fp32 (ws-gated);
// stage12 reads windows straight from E2 (no e-LDS, ONE barrier), F fp32 in LDS,
// __launch_bounds__(448,7) -> 4 blocks/CU.

typedef __attribute__((ext_vector_type(8))) short short8;
typedef __attribute__((ext_vector_type(4))) float f32x4;

__device__ __forceinline__ float fast_tanh(float x) {
    float e = __expf(2.f * x);          // tanh = 1 - 2/(e^{2x}+1); saturates at +-inf
    return 1.f - 2.f / (e + 1.f);
}

__device__ __forceinline__ unsigned fkey(float f) {
    unsigned u = __float_as_uint(f);
    return (u & 0x80000000u) ? ~u : (u | 0x80000000u);   // monotone order-preserving key
}

__device__ __forceinline__ float fkey_inv(unsigned k) {
    unsigned u = (k & 0x80000000u) ? (k ^ 0x80000000u) : ~k;
    return __uint_as_float(u);
}

__device__ __forceinline__ unsigned short f2bf_rne(float f) {
    unsigned u = __float_as_uint(f);
    return (unsigned short)((u + 0x7fffu + ((u >> 16) & 1u)) >> 16);
}

// ---------------- Stage 0: coalesced gather -> E2[b][p 0..63][l 0..1023][4ch] fp32 ----
// grid = 32*16 (b, 64-token chunk), 256 thr. Wave reads one 1 KB emb row; lane p keeps
// channels 4p..4p+3 (= plane p's record). Per-lane stores form contiguous 256 B runs.
__global__ __launch_bounds__(256) void gather_kernel(
    const int* __restrict__ x, const float* __restrict__ emb, float* __restrict__ E2)
{
    const int b = blockIdx.x >> 4;
    const int c64 = blockIdx.x & 15;
    const int wv = threadIdx.x >> 6, lane = threadIdx.x & 63;
    float* dst = E2 + ((((size_t)b << 6) + lane) << 12);   // plane (b,lane): 1024*4 floats
#pragma unroll
    for (int t = 0; t < 16; ++t) {
        int l = (c64 << 6) + (wv << 4) + t;
        int tok = x[(b << 10) + l];                         // wave-uniform -> scalar load
        float4 v = *(const float4*)(emb + ((size_t)tok << 8) + (lane << 2));  // 1 KB/wave
        *(float4*)(dst + (size_t)l * 4) = v;
    }
}

// window fetch: channels (2*half, 2*half+1) of col-group r2 at token l (0 outside [0,1024))
__device__ __forceinline__ float2 win_fetch(const float* __restrict__ E2blk,
                                            const int* __restrict__ xb,
                                            const float* __restrict__ emb,
                                            int r2, int l, int half)
{
    float4 v = {0.f, 0.f, 0.f, 0.f};
    if (l >= 0 && l < 1024) {
        if (E2blk) v = *(const float4*)(E2blk + (size_t)l * 4);
        else {
            int tok = xb[l];
            v = *(const float4*)(emb + ((size_t)tok << 8) + (r2 << 2));
        }
    }
    return half ? float2{v.z, v.w} : float2{v.x, v.y};
}

// ---------------- Fused: conv1 + fold + kmax(515) + tanh + conv2 + fold + kmax(4) + tanh ----------
// grid = 32*64 blocks (b, r2), 448 threads = 7 waves, ONE __syncthreads.
__global__ __launch_bounds__(448, 7) void stage12_kernel(
    const int* __restrict__ x, const float* __restrict__ emb,
    const float* __restrict__ w1, const float* __restrict__ b1,
    const float* __restrict__ w2, const float* __restrict__ b2,
    const float* __restrict__ E2,                   // null -> fallback direct gather
    __hip_bfloat16* __restrict__ H)
{
    __shared__ __align__(16) float F[12 * 584];     // 28,032 B; F[i][4+pos], pos in [0,515)
    const int b = blockIdx.x >> 6;
    const int r2 = blockIdx.x & 63;
    const int tid = threadIdx.x;
    const int w = tid >> 6;
    const int lane = tid & 63;
    const float* E2blk = E2 ? (E2 + ((((size_t)b << 6) + r2) << 12)) : nullptr;
    const int* xb = x + (b << 10);

    // Phase B: rows {w, w+7} (<12): zero own row, conv1+fold, radix-select 515, tanh -> F
    for (int rep = 0; rep < 2; ++rep) {
        const int i = w + rep * 7;
        if (i < 12) {
            float* Frow = F + i * 584;
            for (int t = lane; t < 584; t += 64) Frow[t] = 0.f;   // own-wave row, no barrier

            const int half = (i >= 6) ? 1 : 0;
            const int f = i - 6 * half;
            const int c0 = __builtin_amdgcn_readfirstlane((2 * (2 * r2 + half)) * 6 + f);
            const int c1 = c0 + 6;
            float wA[7], wB[7];
#pragma unroll
            for (int t = 0; t < 7; ++t) { wA[t] = w1[c0 * 7 + t]; wB[t] = w1[c1 * 7 + t]; }
            const float bias = b1[c0] + b1[c1];

            const int pos0 = lane * 17;                   // 17 contiguous outputs/lane
            float a0[7], a1[7];                           // rolling window: l = p-6..p
#pragma unroll
            for (int t = 0; t < 7; ++t) {
                float2 p = win_fetch(E2blk, xb, emb, r2, pos0 - 6 + t, half);
                a0[t] = p.x; a1[t] = p.y;
            }

            unsigned key[17];
#pragma unroll
            for (int j = 0; j < 17; ++j) {
                float a = bias;
#pragma unroll
                for (int t = 0; t < 7; ++t) a += a0[t] * wA[t] + a1[t] * wB[t];
                key[j] = (pos0 + j < 1030) ? fkey(a) : 0u;    // pads below any real key
                if (j < 16) {
#pragma unroll
                    for (int t = 0; t < 6; ++t) { a0[t] = a0[t + 1]; a1[t] = a1[t + 1]; }
                    float2 p = win_fetch(E2blk, xb, emb, r2, pos0 + j + 1, half);
                    a0[6] = p.x; a1[6] = p.y;
                }
            }

            // exact radix-select of 515th-largest key; early exit when set separated
            unsigned T = 0u;
            for (int bit = 31; bit >= 0; --bit) {
                unsigned cand = T | (1u << bit);
                int cnt = 0;
#pragma unroll
                for (int j = 0; j < 17; ++j) cnt += (int)__popcll(__ballot(key[j] >= cand));
                if (cnt >= 515) T = cand;
                if (cnt == 515) break;
            }

            // order-preserving compaction: all >T plus first (515-#gt) ==T in index order
            const unsigned long long lm = (1ull << lane) - 1ull;
            int gt_tot = 0, gt_run = 0, eq_run = 0;
#pragma unroll
            for (int j = 0; j < 17; ++j) {
                unsigned long long bg = __ballot(key[j] > T);
                unsigned long long be = __ballot(key[j] == T);
                gt_tot += (int)__popcll(bg);
                gt_run += (int)__popcll(bg & lm);
                eq_run += (int)__popcll(be & lm);
            }
            const int q = 515 - gt_tot;
#pragma unroll
            for (int j = 0; j < 17; ++j) {
                bool isgt = key[j] > T;
                bool iseq = key[j] == T;
                int pos = gt_run + (eq_run < q ? eq_run : q);
                if (isgt || (iseq && eq_run < q)) Frow[4 + pos] = fast_tanh(fkey_inv(key[j]));
                gt_run += isgt ? 1 : 0;
                eq_run += iseq ? 1 : 0;
            }
        }
    }
    __syncthreads();

    // Phase C: channels {w, w+7}: conv2+fold, kmax4 + tanh -> H
    for (int rep = 0; rep < 2; ++rep) {
        const int j = w + rep * 7;
        const int base = lane * 9;                            // 9 outputs/lane, 576 >= 519
        const int bidx = __builtin_amdgcn_readfirstlane((2 * r2) * 14 + j);
        const float bias2 = b2[bidx] + b2[bidx + 14];
        float acc[9];
#pragma unroll
        for (int jj = 0; jj < 9; ++jj) acc[jj] = bias2;

#pragma unroll
        for (int i = 0; i < 12; ++i) {
            const float* Fr = F + i * 584 + base;             // y[p] = sum_t row[p+t]
            const int cg = 2 * r2 + ((i >= 6) ? 1 : 0);
            const int ii = (i >= 6) ? (i - 6) : i;
            const int widx = __builtin_amdgcn_readfirstlane(((cg * 14 + j) * 6 + ii) * 5);
            float wv[5];
#pragma unroll
            for (int t = 0; t < 5; ++t) wv[t] = w2[widx + t];
            float win[5];
#pragma unroll
            for (int t = 0; t < 5; ++t) win[t] = Fr[t];
#pragma unroll
            for (int jj = 0; jj < 9; ++jj) {
#pragma unroll
                for (int t = 0; t < 5; ++t) acc[jj] += win[t] * wv[t];
                if (jj < 8) {
#pragma unroll
                    for (int t = 0; t < 4; ++t) win[t] = win[t + 1];
                    win[4] = Fr[jj + 5];
                }
            }
        }

        float vv[9];
#pragma unroll
        for (int jj = 0; jj < 9; ++jj) vv[jj] = (base + jj < 519) ? acc[jj] : -INFINITY;
        float sv[4]; int si[4];
#pragma unroll
        for (int it = 0; it < 4; ++it) {
            float m = vv[0]; int mi = base;
#pragma unroll
            for (int jj = 1; jj < 9; ++jj) { if (vv[jj] > m) { m = vv[jj]; mi = base + jj; } }
#pragma unroll
            for (int d = 1; d < 64; d <<= 1) {
                float om = __shfl_xor(m, d, 64);
                int omi = __shfl_xor(mi, d, 64);
                if (om > m || (om == m && omi < mi)) { m = om; mi = omi; }
            }
            sv[it] = m; si[it] = mi;
            int lj = mi - base;
#pragma unroll
            for (int jj = 0; jj < 9; ++jj) if (jj == lj) vv[jj] = -INFINITY;
        }
#define CSWAP(a, bq) { if (si[a] > si[bq]) { int ti = si[a]; si[a] = si[bq]; si[bq] = ti; \
                                             float tv = sv[a]; sv[a] = sv[bq]; sv[bq] = tv; } }
        CSWAP(0, 1) CSWAP(2, 3) CSWAP(0, 2) CSWAP(1, 3) CSWAP(1, 2)
#undef CSWAP
        if (lane == 0) {
            __hip_bfloat16* op = H + (size_t)b * 3584 + (r2 * 14 + j) * 4;
#pragma unroll
            for (int k = 0; k < 4; ++k) op[k] = __float2bfloat16(fast_tanh(sv[k]));
        }
    }
}

// ---------------- Stage 3: (32x3584) @ wf^T (3584x1000) + bf via MFMA, K split 4 ways ----------------
__global__ __launch_bounds__(256) void bias_init_kernel(
    const float* __restrict__ bfv, float* __restrict__ out)
{
    int idx = blockIdx.x * 256 + threadIdx.x;
    if (idx < 32000) out[idx] = bfv[idx - (idx / 1000) * 1000];
}

__global__ __launch_bounds__(256) void stage3_kernel(
    const __hip_bfloat16* __restrict__ Hb, const float* __restrict__ wf,
    float* __restrict__ out)
{
    __shared__ __align__(16) float sred[2 * 4 * 256];
    const int nt = blockIdx.x % 63;
    const int kc = blockIdx.x / 63;
    const int w = threadIdx.x >> 6, lane = threadIdx.x & 63;
    const int row = lane & 15, quad = lane >> 4;
    const int c = nt * 16 + row;
    const bool cvalid = (c < 1000);
    const int kofs = kc * 896 + w * 224 + quad * 8;
    const __hip_bfloat16* ap0 = Hb + (size_t)row * 3584 + kofs;
    const __hip_bfloat16* ap1 = ap0 + (size_t)16 * 3584;
    const float* bp = wf + (size_t)(cvalid ? c : 0) * 3584 + kofs;

    f32x4 acc0 = {0.f, 0.f, 0.f, 0.f};
    f32x4 acc1 = {0.f, 0.f, 0.f, 0.f};
#pragma unroll
    for (int it = 0; it < 7; ++it) {
        short8 a0 = *(const short8*)(ap0 + it * 32);
        short8 a1 = *(const short8*)(ap1 + it * 32);
        float4 p0 = *(const float4*)(bp + it * 32);
        float4 p1 = *(const float4*)(bp + it * 32 + 4);
        short8 bfr;
        bfr[0] = (short)f2bf_rne(p0.x); bfr[1] = (short)f2bf_rne(p0.y);
        bfr[2] = (short)f2bf_rne(p0.z); bfr[3] = (short)f2bf_rne(p0.w);
        bfr[4] = (short)f2bf_rne(p1.x); bfr[5] = (short)f2bf_rne(p1.y);
        bfr[6] = (short)f2bf_rne(p1.z); bfr[7] = (short)f2bf_rne(p1.w);
        if (!cvalid) bfr = short8{0, 0, 0, 0, 0, 0, 0, 0};
        acc0 = __builtin_amdgcn_mfma_f32_16x16x32_bf16(a0, bfr, acc0, 0, 0, 0);
        acc1 = __builtin_amdgcn_mfma_f32_16x16x32_bf16(a1, bfr, acc1, 0, 0, 0);
    }
#pragma unroll
    for (int r_ = 0; r_ < 4; ++r_) {
        sred[(0 * 4 + w) * 256 + lane * 4 + r_] = acc0[r_];
        sred[(1 * 4 + w) * 256 + lane * 4 + r_] = acc1[r_];
    }
    __syncthreads();
    if (threadIdx.x < 128) {
        const int mt = threadIdx.x >> 6;
        const int l2 = threadIdx.x & 63;
        const int rr = l2 & 15, qq = l2 >> 4;
        const int cc = nt * 16 + rr;
        if (cc < 1000) {
            const float* sp = sred + mt * 4 * 256;
#pragma unroll
            for (int r_ = 0; r_ < 4; ++r_) {
                float s = sp[0 * 256 + l2 * 4 + r_] + sp[1 * 256 + l2 * 4 + r_]
                        + sp[2 * 256 + l2 * 4 + r_] + sp[3 * 256 + l2 * 4 + r_];
                int brow = mt * 16 + qq * 4 + r_;
                atomicAdd(&out[brow * 1000 + cc], s);
            }
        }
    }
}

extern "C" void kernel_launch(void* const* d_in, const int* in_sizes, int n_in,
                              void* d_out, int out_size, void* d_ws, size_t ws_size,
                              hipStream_t stream) {
    const int* x      = (const int*)d_in[0];
    const float* emb  = (const float*)d_in[1];
    const float* w1   = (const float*)d_in[2];
    const float* b1   = (const float*)d_in[3];
    const float* w2   = (const float*)d_in[4];
    const float* b2   = (const float*)d_in[5];
    const float* wf   = (const float*)d_in[6];
    const float* bfv  = (const float*)d_in[7];

    const size_t E2_BYTES = (size_t)32 * 64 * 1024 * 4 * 4;   // 33,554,432 (fp32)
    const size_t H_BYTES  = (size_t)32 * 3584 * 2;            // 229,376
    float* E2 = nullptr;
    __hip_bfloat16* H;
    if (ws_size >= E2_BYTES + H_BYTES) {
        E2 = (float*)d_ws;
        H = (__hip_bfloat16*)((char*)d_ws + E2_BYTES);
    } else {
        H = (__hip_bfloat16*)d_ws;
    }

    bias_init_kernel<<<125, 256, 0, stream>>>(bfv, (float*)d_out);
    if (E2) gather_kernel<<<32 * 16, 256, 0, stream>>>(x, emb, E2);
    stage12_kernel<<<32 * 64, 448, 0, stream>>>(x, emb, w1, b1, w2, b2, E2, H);
    stage3_kernel<<<63 * 4, 256, 0, stream>>>(H, wf, (float*)d_out);
}

// Round 7
// 259.782 us; speedup vs baseline: 3.7079x; 3.7079x over previous
//
#include <hip/hip_runtime.h>
#include <hip/hip_bf16.h>

// Shapes: B=32 S=1024 D=256 V=50257 C=1000   (float tensors fp32; x int32; out fp32)
// conv1: groups=256, Cin/g=1, Cout/g=6, K=7, pad=6 -> L1=1030; fold -> 768 ch
// kmax k1=515 -> tanh -> conv2: groups=128, Cin/g=6, Cout/g=14, K=5, pad=4 -> L2=519
// fold -> 896 ch -> kmax 4 -> tanh -> (32,3584) @ wf^T(1000,3584) + bf
//
// R7 = R4 (proven 202 us, no spills) + coalesced E2 gather feeding a contiguous
// phase-A LDS fill + exact early-exit radix select. R6 lesson: hot unrolled windows
// MUST be fed branchlessly from LDS or SROA fails and arrays spill to scratch
// (R6: 1.48 GB FETCH + 1.28 GB WRITE of scratch traffic, 4.3x regression).

typedef __attribute__((ext_vector_type(8))) short short8;
typedef __attribute__((ext_vector_type(4))) float f32x4;

__device__ __forceinline__ float fast_tanh(float x) {
    float e = __expf(2.f * x);          // tanh = 1 - 2/(e^{2x}+1); saturates at +-inf
    return 1.f - 2.f / (e + 1.f);
}

__device__ __forceinline__ unsigned fkey(float f) {
    unsigned u = __float_as_uint(f);
    return (u & 0x80000000u) ? ~u : (u | 0x80000000u);   // monotone order-preserving key
}

__device__ __forceinline__ float fkey_inv(unsigned k) {
    unsigned u = (k & 0x80000000u) ? (k ^ 0x80000000u) : ~k;
    return __uint_as_float(u);
}

__device__ __forceinline__ unsigned short f2bf_rne(float f) {
    unsigned u = __float_as_uint(f);
    return (unsigned short)((u + 0x7fffu + ((u >> 16) & 1u)) >> 16);
}

// ---------------- Stage 0: coalesced gather -> E2[b][p 0..63][l 0..1023][4ch] fp32 ----
// grid = 32*16 (b, 64-token chunk), 256 thr. Wave reads one 1 KB emb row; lane p keeps
// channels 4p..4p+3 (plane p). Per-lane stores form contiguous 256 B runs.
__global__ __launch_bounds__(256) void gather_kernel(
    const int* __restrict__ x, const float* __restrict__ emb, float* __restrict__ E2)
{
    const int b = blockIdx.x >> 4;
    const int c64 = blockIdx.x & 15;
    const int wv = threadIdx.x >> 6, lane = threadIdx.x & 63;
    float* dst = E2 + ((((size_t)b << 6) + lane) << 12);   // plane (b,lane): 1024*4 floats
#pragma unroll
    for (int t = 0; t < 16; ++t) {
        int l = (c64 << 6) + (wv << 4) + t;
        int tok = x[(b << 10) + l];                         // wave-uniform -> scalar load
        float4 v = *(const float4*)(emb + ((size_t)tok << 8) + (lane << 2));  // 1 KB/wave
        *(float4*)(dst + (size_t)l * 4) = v;
    }
}

// ---------------- Fused: conv1 + fold + kmax(515) + tanh + conv2 + fold + kmax(4) + tanh ----------
// grid = 32*64 blocks (b, r2), 896 threads = 14 waves (round-4 shape).
__global__ __launch_bounds__(896) void stage12_kernel(
    const int* __restrict__ x, const float* __restrict__ emb,
    const float* __restrict__ w1, const float* __restrict__ b1,
    const float* __restrict__ w2, const float* __restrict__ b2,
    const float* __restrict__ E2,                   // null -> fallback direct gather
    __hip_bfloat16* __restrict__ H)
{
    __shared__ __align__(16) float e[4 * 1104];     // 4 emb channels, padded (idx = l+6)
    __shared__ __align__(16) float F[12 * 584];     // F[i][4+pos], pos in [0,515)
    const int b = blockIdx.x >> 6;
    const int r2 = blockIdx.x & 63;
    const int tid = threadIdx.x;

    // Phase A: zero F, fill e. E2 path: contiguous float4 per thread (coalesced).
    for (int i = tid; i < 12 * 584; i += 896) F[i] = 0.f;
    if (E2) {
        const float* E2blk = E2 + ((((size_t)b << 6) + r2) << 12);
        for (int idx = tid; idx < 1104; idx += 896) {
            int l = idx - 6;
            float4 v = {0.f, 0.f, 0.f, 0.f};
            if (l >= 0 && l < 1024) v = *(const float4*)(E2blk + (size_t)l * 4);
            e[0 * 1104 + idx] = v.x; e[1 * 1104 + idx] = v.y;
            e[2 * 1104 + idx] = v.z; e[3 * 1104 + idx] = v.w;
        }
    } else {
        for (int idx = tid; idx < 1104; idx += 896) {
            int l = idx - 6;
            float4 v = {0.f, 0.f, 0.f, 0.f};
            if (l >= 0 && l < 1024) {
                int tok = x[(b << 10) + l];
                v = *(const float4*)(emb + ((size_t)tok << 8) + (r2 << 2));
            }
            e[0 * 1104 + idx] = v.x; e[1 * 1104 + idx] = v.y;
            e[2 * 1104 + idx] = v.z; e[3 * 1104 + idx] = v.w;
        }
    }
    __syncthreads();

    const int w = tid >> 6;
    const int lane = tid & 63;

    // Phase B: waves 0..11 -> folded conv1 row i=w, exact radix-select 515, tanh -> F
    if (w < 12) {
        const int half = (w >= 6) ? 1 : 0;
        const int f = w - half * 6;
        const float* ep0 = e + (2 * half) * 1104;     // emb ch 4*r2 + 2*half
        const float* ep1 = ep0 + 1104;
        const int c0 = __builtin_amdgcn_readfirstlane((2 * (2 * r2 + half)) * 6 + f);
        const int c1 = c0 + 6;
        float wA[7], wB[7];
#pragma unroll
        for (int t = 0; t < 7; ++t) { wA[t] = w1[c0 * 7 + t]; wB[t] = w1[c1 * 7 + t]; }
        const float bias = b1[c0] + b1[c1];

        const int pos0 = lane * 17;                   // 17 contiguous outputs/lane
        float a0[7], a1[7];                           // rolling window (LDS-fed, branchless)
#pragma unroll
        for (int t = 0; t < 7; ++t) { a0[t] = ep0[pos0 + t]; a1[t] = ep1[pos0 + t]; }

        unsigned key[17];
#pragma unroll
        for (int j = 0; j < 17; ++j) {
            float a = bias;
#pragma unroll
            for (int t = 0; t < 7; ++t) a += a0[t] * wA[t] + a1[t] * wB[t];
            key[j] = (pos0 + j < 1030) ? fkey(a) : 0u;    // pads below any real key
            if (j < 16) {
#pragma unroll
                for (int t = 0; t < 6; ++t) { a0[t] = a0[t + 1]; a1[t] = a1[t + 1]; }
                a0[6] = ep0[pos0 + j + 7];
                a1[6] = ep1[pos0 + j + 7];
            }
        }

        // exact radix-select of 515th-largest key; early exit when the set separates
        // (cnt_ge(cand)==515 -> {key>=cand} IS the top-515; tie-compaction unchanged)
        unsigned T = 0u;
        for (int bit = 31; bit >= 0; --bit) {
            unsigned cand = T | (1u << bit);
            int cnt = 0;
#pragma unroll
            for (int j = 0; j < 17; ++j) cnt += (int)__popcll(__ballot(key[j] >= cand));
            if (cnt >= 515) T = cand;
            if (cnt == 515) break;
        }

        // order-preserving compaction: all >T plus first (515-#gt) ==T in index order
        const unsigned long long lm = (1ull << lane) - 1ull;
        int gt_tot = 0, gt_run = 0, eq_run = 0;
#pragma unroll
        for (int j = 0; j < 17; ++j) {
            unsigned long long bg = __ballot(key[j] > T);
            unsigned long long be = __ballot(key[j] == T);
            gt_tot += (int)__popcll(bg);
            gt_run += (int)__popcll(bg & lm);
            eq_run += (int)__popcll(be & lm);
        }
        const int q = 515 - gt_tot;
        float* Frow = F + w * 584;
#pragma unroll
        for (int j = 0; j < 17; ++j) {
            bool isgt = key[j] > T;
            bool iseq = key[j] == T;
            int pos = gt_run + (eq_run < q ? eq_run : q);
            if (isgt || (iseq && eq_run < q)) Frow[4 + pos] = fast_tanh(fkey_inv(key[j]));
            gt_run += isgt ? 1 : 0;
            eq_run += iseq ? 1 : 0;
        }
    }
    __syncthreads();

    // Phase C: wave w -> folded conv2 channel j=w, kmax4 + tanh -> H
    {
        const int j = w;
        const int base = lane * 9;                            // 9 outputs/lane, 576 >= 519
        const int bidx = __builtin_amdgcn_readfirstlane((2 * r2) * 14 + j);
        const float bias2 = b2[bidx] + b2[bidx + 14];
        float acc[9];
#pragma unroll
        for (int jj = 0; jj < 9; ++jj) acc[jj] = bias2;

#pragma unroll
        for (int i = 0; i < 12; ++i) {
            const float* Fr = F + i * 584 + base;             // y[p] = sum_t row[p+t]
            const int cg = 2 * r2 + ((i >= 6) ? 1 : 0);
            const int ii = (i >= 6) ? (i - 6) : i;
            const int widx = __builtin_amdgcn_readfirstlane(((cg * 14 + j) * 6 + ii) * 5);
            float wv[5];
#pragma unroll
            for (int t = 0; t < 5; ++t) wv[t] = w2[widx + t];
            float win[5];
#pragma unroll
            for (int t = 0; t < 5; ++t) win[t] = Fr[t];
#pragma unroll
            for (int jj = 0; jj < 9; ++jj) {
#pragma unroll
                for (int t = 0; t < 5; ++t) acc[jj] += win[t] * wv[t];
                if (jj < 8) {
#pragma unroll
                    for (int t = 0; t < 4; ++t) win[t] = win[t + 1];
                    win[4] = Fr[jj + 5];
                }
            }
        }

        float vv[9];
#pragma unroll
        for (int jj = 0; jj < 9; ++jj) vv[jj] = (base + jj < 519) ? acc[jj] : -INFINITY;
        float sv[4]; int si[4];
#pragma unroll
        for (int it = 0; it < 4; ++it) {
            float m = vv[0]; int mi = base;
#pragma unroll
            for (int jj = 1; jj < 9; ++jj) { if (vv[jj] > m) { m = vv[jj]; mi = base + jj; } }
#pragma unroll
            for (int d = 1; d < 64; d <<= 1) {
                float om = __shfl_xor(m, d, 64);
                int omi = __shfl_xor(mi, d, 64);
                if (om > m || (om == m && omi < mi)) { m = om; mi = omi; }
            }
            sv[it] = m; si[it] = mi;
            int lj = mi - base;
#pragma unroll
            for (int jj = 0; jj < 9; ++jj) if (jj == lj) vv[jj] = -INFINITY;
        }
#define CSWAP(a, bq) { if (si[a] > si[bq]) { int ti = si[a]; si[a] = si[bq]; si[bq] = ti; \
                                             float tv = sv[a]; sv[a] = sv[bq]; sv[bq] = tv; } }
        CSWAP(0, 1) CSWAP(2, 3) CSWAP(0, 2) CSWAP(1, 3) CSWAP(1, 2)
#undef CSWAP
        if (lane == 0) {
            __hip_bfloat16* op = H + (size_t)b * 3584 + (r2 * 14 + j) * 4;
#pragma unroll
            for (int k = 0; k < 4; ++k) op[k] = __float2bfloat16(fast_tanh(sv[k]));
        }
    }
}

// ---------------- Stage 3: (32x3584) @ wf^T (3584x1000) + bf via MFMA, K split 4 ways ----------------
__global__ __launch_bounds__(256) void bias_init_kernel(
    const float* __restrict__ bfv, float* __restrict__ out)
{
    int idx = blockIdx.x * 256 + threadIdx.x;
    if (idx < 32000) out[idx] = bfv[idx - (idx / 1000) * 1000];
}

__global__ __launch_bounds__(256) void stage3_kernel(
    const __hip_bfloat16* __restrict__ Hb, const float* __restrict__ wf,
    float* __restrict__ out)
{
    __shared__ __align__(16) float sred[2 * 4 * 256];
    const int nt = blockIdx.x % 63;
    const int kc = blockIdx.x / 63;
    const int w = threadIdx.x >> 6, lane = threadIdx.x & 63;
    const int row = lane & 15, quad = lane >> 4;
    const int c = nt * 16 + row;
    const bool cvalid = (c < 1000);
    const int kofs = kc * 896 + w * 224 + quad * 8;
    const __hip_bfloat16* ap0 = Hb + (size_t)row * 3584 + kofs;
    const __hip_bfloat16* ap1 = ap0 + (size_t)16 * 3584;
    const float* bp = wf + (size_t)(cvalid ? c : 0) * 3584 + kofs;

    f32x4 acc0 = {0.f, 0.f, 0.f, 0.f};
    f32x4 acc1 = {0.f, 0.f, 0.f, 0.f};
#pragma unroll
    for (int it = 0; it < 7; ++it) {
        short8 a0 = *(const short8*)(ap0 + it * 32);
        short8 a1 = *(const short8*)(ap1 + it * 32);
        float4 p0 = *(const float4*)(bp + it * 32);
        float4 p1 = *(const float4*)(bp + it * 32 + 4);
        short8 bfr;
        bfr[0] = (short)f2bf_rne(p0.x); bfr[1] = (short)f2bf_rne(p0.y);
        bfr[2] = (short)f2bf_rne(p0.z); bfr[3] = (short)f2bf_rne(p0.w);
        bfr[4] = (short)f2bf_rne(p1.x); bfr[5] = (short)f2bf_rne(p1.y);
        bfr[6] = (short)f2bf_rne(p1.z); bfr[7] = (short)f2bf_rne(p1.w);
        if (!cvalid) bfr = short8{0, 0, 0, 0, 0, 0, 0, 0};
        acc0 = __builtin_amdgcn_mfma_f32_16x16x32_bf16(a0, bfr, acc0, 0, 0, 0);
        acc1 = __builtin_amdgcn_mfma_f32_16x16x32_bf16(a1, bfr, acc1, 0, 0, 0);
    }
#pragma unroll
    for (int r_ = 0; r_ < 4; ++r_) {
        sred[(0 * 4 + w) * 256 + lane * 4 + r_] = acc0[r_];
        sred[(1 * 4 + w) * 256 + lane * 4 + r_] = acc1[r_];
    }
    __syncthreads();
    if (threadIdx.x < 128) {
        const int mt = threadIdx.x >> 6;
        const int l2 = threadIdx.x & 63;
        const int rr = l2 & 15, qq = l2 >> 4;
        const int cc = nt * 16 + rr;
        if (cc < 1000) {
            const float* sp = sred + mt * 4 * 256;
#pragma unroll
            for (int r_ = 0; r_ < 4; ++r_) {
                float s = sp[0 * 256 + l2 * 4 + r_] + sp[1 * 256 + l2 * 4 + r_]
                        + sp[2 * 256 + l2 * 4 + r_] + sp[3 * 256 + l2 * 4 + r_];
                int brow = mt * 16 + qq * 4 + r_;
                atomicAdd(&out[brow * 1000 + cc], s);
            }
        }
    }
}

extern "C" void kernel_launch(void* const* d_in, const int* in_sizes, int n_in,
                              void* d_out, int out_size, void* d_ws, size_t ws_size,
                              hipStream_t stream) {
    const int* x      = (const int*)d_in[0];
    const float* emb  = (const float*)d_in[1];
    const float* w1   = (const float*)d_in[2];
    const float* b1   = (const float*)d_in[3];
    const float* w2   = (const float*)d_in[4];
    const float* b2   = (const float*)d_in[5];
    const float* wf   = (const float*)d_in[6];
    const float* bfv  = (const float*)d_in[7];

    const size_t E2_BYTES = (size_t)32 * 64 * 1024 * 4 * 4;   // 33,554,432 (fp32)
    const size_t H_BYTES  = (size_t)32 * 3584 * 2;            // 229,376
    float* E2 = nullptr;
    __hip_bfloat16* H;
    if (ws_size >= E2_BYTES + H_BYTES) {
        E2 = (float*)d_ws;
        H = (__hip_bfloat16*)((char*)d_ws + E2_BYTES);
    } else {
        H = (__hip_bfloat16*)d_ws;
    }

    bias_init_kernel<<<125, 256, 0, stream>>>(bfv, (float*)d_out);
    if (E2) gather_kernel<<<32 * 16, 256, 0, stream>>>(x, emb, E2);
    stage12_kernel<<<32 * 64, 896, 0, stream>>>(x, emb, w1, b1, w2, b2, E2, H);
    stage3_kernel<<<63 * 4, 256, 0, stream>>>(H, wf, (float*)d_out);
}